// Round 15
// baseline (375.057 us; speedup 1.0000x reference)
//
#include <hip/hip_runtime.h>

#define L_TOK   169536
#define LPAD    169984
#define NCHUNK  166
#define FLT_L   169536.0f

typedef __attribute__((ext_vector_type(8))) short bfrag;
typedef __attribute__((ext_vector_type(4))) short short4_t;
typedef __attribute__((ext_vector_type(4))) float f32x4;
typedef __attribute__((ext_vector_type(4))) float float4_t;

__device__ __forceinline__ ushort f2bf(float f){
  unsigned u = __float_as_uint(f);
  u += 0x7fffu + ((u >> 16) & 1u);
  return (ushort)(u >> 16);
}
__device__ __forceinline__ float bf2f(ushort h){ return __uint_as_float(((unsigned)h) << 16); }

__device__ __forceinline__ f32x4 MFMA(bfrag a, bfrag b, f32x4 c){
  return __builtin_amdgcn_mfma_f32_16x16x32_bf16(a, b, c, 0, 0, 0);
}

// ---------------- kernel 1: transpose weights to bf16 [512][128] ----------------
__global__ __launch_bounds__(256) void prep_w_kernel(const float* __restrict__ wq, const float* __restrict__ wk,
                                                     const float* __restrict__ wv, ushort* __restrict__ wqT,
                                                     ushort* __restrict__ wkT, ushort* __restrict__ wvT){
  int t = blockIdx.x * 256 + threadIdx.x;        // 3*65536 threads
  int mat = t >> 16;
  int idx = t & 65535;
  int n = idx >> 7, i = idx & 127;
  const float* w = (mat == 0) ? wq : (mat == 1) ? wk : wv;
  ushort* o = (mat == 0) ? wqT : (mat == 1) ? wkT : wvT;
  o[idx] = f2bf(w[i * 512 + n]);                 // WT[n][i] = W[i][n]
}

// ---------------- kernel 2: h = relu(LN(x @ fc0_w + b)) -> bf16 [LPAD][128] ----------------
__global__ __launch_bounds__(256) void fc0_kernel(const float* __restrict__ x, const float* __restrict__ w,
                                                  const float* __restrict__ bias, const float* __restrict__ g,
                                                  const float* __restrict__ be, ushort* __restrict__ hbf){
  __shared__ float wl[8192];                      // [64 k][128 ch] fp32, 32KB
  __shared__ float xs[2048];                      // [32 tok][64 k] fp32, 8KB
  int tid = threadIdx.x;
  #pragma unroll
  for (int j = 0; j < 8; ++j) ((float4_t*)wl)[tid + j * 256] = ((const float4_t*)w)[tid + j * 256];
  int tok0 = blockIdx.x * 32;                     // L_TOK % 32 == 0: blocks fully valid or fully invalid
  bool blk_valid = (tok0 + 32) <= L_TOK;
  if (blk_valid){
    const float4_t* xsrc = (const float4_t*)(x + (size_t)tok0 * 64);
    ((float4_t*)xs)[tid] = xsrc[tid];
    ((float4_t*)xs)[tid + 256] = xsrc[tid + 256];
  }
  __syncthreads();
  int wv = tid >> 6, ln = tid & 63;
  if (!blk_valid){
    for (int t = 0; t < 8; ++t){
      size_t tok = (size_t)tok0 + wv * 8 + t;
      hbf[tok * 128 + ln] = 0; hbf[tok * 128 + ln + 64] = 0;
    }
    return;
  }
  float b0 = bias[ln], b1 = bias[ln + 64];
  float g0 = g[ln], g1v = g[ln + 64], e0 = be[ln], e1 = be[ln + 64];
  for (int t = 0; t < 8; ++t){
    int tokl = wv * 8 + t;
    float a0 = b0, a1 = b1;
    #pragma unroll
    for (int i4 = 0; i4 < 16; ++i4){
      float4_t xv = *(const float4_t*)(xs + tokl * 64 + i4 * 4);  // wave-uniform -> LDS broadcast
      #pragma unroll
      for (int u = 0; u < 4; ++u){
        a0 = fmaf(xv[u], wl[(i4 * 4 + u) * 128 + ln], a0);
        a1 = fmaf(xv[u], wl[(i4 * 4 + u) * 128 + ln + 64], a1);
      }
    }
    float s = a0 + a1;
    #pragma unroll
    for (int m = 1; m < 64; m <<= 1) s += __shfl_xor(s, m);
    float mean = s * 0.0078125f;
    float d0 = a0 - mean, d1 = a1 - mean;
    float ss = d0 * d0 + d1 * d1;
    #pragma unroll
    for (int m = 1; m < 64; m <<= 1) ss += __shfl_xor(ss, m);
    float rstd = rsqrtf(ss * 0.0078125f + 1e-5f);
    float y0 = fmaxf(fmaf(d0 * rstd, g0, e0), 0.f);
    float y1 = fmaxf(fmaf(d1 * rstd, g1v, e1), 0.f);
    size_t tok = (size_t)tok0 + tokl;
    hbf[tok * 128 + ln] = f2bf(y0);
    hbf[tok * 128 + ln + 64] = f2bf(y1);
  }
}

// ---------------- kernel 3: 8-wave token-split (chunk, head) kv kernel, spill-free ----------------
__global__ __launch_bounds__(512) void kv_kernel(const ushort* __restrict__ hbf, const ushort* __restrict__ wkT,
                                                 const ushort* __restrict__ wvT, const float* __restrict__ bk,
                                                 const float* __restrict__ bv, float* __restrict__ kvsP,
                                                 float* __restrict__ ksvP){
  __shared__ char smem[51200];
  ushort* h_t = (ushort*)smem;                    // [64 tok][128 i] bf16, swizzled, 16KB
  char* kT = smem + 16384;                        // [128 m][64 tok] bf16, swizzled, 16KB
  char* vT = smem + 32768;                        // [128 d][64 tok]
  float* red = (float*)(smem + 49152);            // [64 tok][4 mq] f32, 1KB (+1KB spare)
  int tid = threadIdx.x, w = tid >> 6, ln = tid & 63;
  int mq = w & 3, th = w >> 2;
  int head = blockIdx.x & 3, chunk = blockIdx.x >> 2;
  int lg = ln >> 4, lc = ln & 15;

  f32x4 zero4 = {0.f, 0.f, 0.f, 0.f};
  f32x4 acc[2][8];                                // kvs partial over this wave's token half
  #pragma unroll
  for (int a = 0; a < 2; ++a)
    #pragma unroll
    for (int b = 0; b < 8; ++b) acc[a][b] = zero4;
  f32x4 acc_ks[2] = {zero4, zero4}, acc_vs[2] = {zero4, zero4};

  bfrag ones;
  #pragma unroll
  for (int j = 0; j < 8; ++j) ones[j] = (short)0x3F80;   // bf16 1.0

  const ushort* WK = wkT + (size_t)(head * 128 + mq * 32 + lc) * 128 + lg * 8;
  const ushort* WV = wvT + (size_t)(head * 128 + mq * 32 + lc) * 128 + lg * 8;
  const float* BK = bk + head * 128 + mq * 32 + lg * 4;
  const float* BV = bv + head * 128 + mq * 32 + lg * 4;

  // prologue: stage tile 0 (16KB) into registers (512 thr x 32B)
  bfrag st[2];
  {
    const char* h0 = (const char*)hbf + (size_t)chunk * 1024 * 256;
    #pragma unroll
    for (int p = 0; p < 2; ++p) st[p] = *(const bfrag*)(h0 + tid * 16 + p * 8192);
  }

  for (int it = 0; it < 16; ++it){
    #pragma unroll
    for (int p = 0; p < 2; ++p){
      int off = tid * 16 + p * 8192;
      int swz = off ^ (((off >> 8) & 7) << 4);
      *(bfrag*)((char*)h_t + swz) = st[p];
    }
    __syncthreads();                              // S1: h_t ready
    if (it < 15){
      const char* hn = (const char*)hbf + ((size_t)chunk * 1024 + (it + 1) * 64) * 256;
      #pragma unroll
      for (int p = 0; p < 2; ++p) st[p] = *(const bfrag*)(hn + tid * 16 + p * 8192);
    }
    int tok0 = chunk * 1024 + it * 64;

    // ---- k GEMM: m-tile [mq*32, +32), tokens [th*32, +32): 16 MFMA ----
    f32x4 ak[2][2];
    #pragma unroll
    for (int a = 0; a < 2; ++a)
      #pragma unroll
      for (int b = 0; b < 2; ++b) ak[a][b] = zero4;
    #pragma unroll
    for (int ks = 0; ks < 4; ++ks){
      bfrag wk0 = *(const bfrag*)(WK + ks * 32);
      bfrag wk1 = *(const bfrag*)(WK + 2048 + ks * 32);
      #pragma unroll
      for (int nt = 0; nt < 2; ++nt){
        int tok = th * 32 + nt * 16 + lc;
        bfrag bb = *(const bfrag*)((char*)h_t + tok * 256 + ((ks * 64 + lg * 16) ^ ((tok & 7) << 4)));
        ak[0][nt] = MFMA(wk0, bb, ak[0][nt]);
        ak[1][nt] = MFMA(wk1, bb, ak[1][nt]);
      }
    }
    // bias (reloaded per use, loop-invariant addr -> L1 hit) + tail-mask + sum-of-squares
    float ss[2];
    {
      float4_t bk0 = *(const float4_t*)(BK);
      float4_t bk1 = *(const float4_t*)(BK + 16);
      #pragma unroll
      for (int nt = 0; nt < 2; ++nt){
        int gtok = tok0 + th * 32 + nt * 16 + lc;
        bool valid = gtok < L_TOK;
        ss[nt] = 0.f;
        #pragma unroll
        for (int r = 0; r < 4; ++r){
          float k0 = valid ? ak[0][nt][r] + bk0[r] : 0.f;
          float k1 = valid ? ak[1][nt][r] + bk1[r] : 0.f;
          ak[0][nt][r] = k0; ak[1][nt][r] = k1;
          ss[nt] += k0 * k0 + k1 * k1;
        }
        ss[nt] += __shfl_xor(ss[nt], 16);
        ss[nt] += __shfl_xor(ss[nt], 32);
      }
    }
    if (ln < 16){
      #pragma unroll
      for (int nt = 0; nt < 2; ++nt) red[(th * 32 + nt * 16 + ln) * 4 + mq] = ss[nt];
    }
    __syncthreads();                              // S2: red ready (each half written by its 4 mq waves)
    float scale[2];
    #pragma unroll
    for (int nt = 0; nt < 2; ++nt){
      float4_t s4 = *(const float4_t*)(red + (th * 32 + nt * 16 + lc) * 4);
      scale[nt] = 1.f / (sqrtf((s4[0] + s4[1]) + (s4[2] + s4[3])) + 1e-8f);
    }
    // write k-hat quadrant
    #pragma unroll
    for (int mt = 0; mt < 2; ++mt)
      #pragma unroll
      for (int r = 0; r < 4; ++r){
        int m = mq * 32 + mt * 16 + lg * 4 + r;
        int sw = (m & 7) << 4;
        #pragma unroll
        for (int nt = 0; nt < 2; ++nt){
          int col = th * 32 + nt * 16 + lc;
          *(ushort*)(kT + m * 128 + ((col * 2) ^ sw)) = f2bf(ak[mt][nt][r] * scale[nt]);
        }
      }

    // ---- v GEMM (reuse ak registers) ----
    #pragma unroll
    for (int a = 0; a < 2; ++a)
      #pragma unroll
      for (int b = 0; b < 2; ++b) ak[a][b] = zero4;
    #pragma unroll
    for (int ks = 0; ks < 4; ++ks){
      bfrag wv0 = *(const bfrag*)(WV + ks * 32);
      bfrag wv1 = *(const bfrag*)(WV + 2048 + ks * 32);
      #pragma unroll
      for (int nt = 0; nt < 2; ++nt){
        int tok = th * 32 + nt * 16 + lc;
        bfrag bb = *(const bfrag*)((char*)h_t + tok * 256 + ((ks * 64 + lg * 16) ^ ((tok & 7) << 4)));
        ak[0][nt] = MFMA(wv0, bb, ak[0][nt]);
        ak[1][nt] = MFMA(wv1, bb, ak[1][nt]);
      }
    }
    {
      float4_t bv0 = *(const float4_t*)(BV);
      float4_t bv1 = *(const float4_t*)(BV + 16);
      #pragma unroll
      for (int nt = 0; nt < 2; ++nt){
        int gtok = tok0 + th * 32 + nt * 16 + lc;
        bool valid = gtok < L_TOK;
        int col = th * 32 + nt * 16 + lc;
        #pragma unroll
        for (int r = 0; r < 4; ++r){
          float v0 = valid ? ak[0][nt][r] + bv0[r] : 0.f;
          float v1 = valid ? ak[1][nt][r] + bv1[r] : 0.f;
          int m0_ = mq * 32 + lg * 4 + r;
          int m1_ = m0_ + 16;
          *(ushort*)(vT + m0_ * 128 + ((col * 2) ^ ((m0_ & 7) << 4))) = f2bf(v0);
          *(ushort*)(vT + m1_ * 128 + ((col * 2) ^ ((m1_ & 7) << 4))) = f2bf(v1);
        }
      }
    }
    __syncthreads();                              // S3: kT/vT ready

    // ---- kvs over this wave's K-window (32 tokens): chunked B-loads to cap liveness ----
    {
      int koff = th * 64 + lg * 16;
      int m0 = mq * 32 + lc, m1 = m0 + 16;
      bfrag a0 = *(const bfrag*)(kT + m0 * 128 + (koff ^ ((m0 & 7) << 4)));
      bfrag a1 = *(const bfrag*)(kT + m1 * 128 + (koff ^ ((m1 & 7) << 4)));
      acc_ks[0] = MFMA(a0, ones, acc_ks[0]);
      acc_ks[1] = MFMA(a1, ones, acc_ks[1]);
      {
        bfrag av0 = *(const bfrag*)(vT + m0 * 128 + (koff ^ ((m0 & 7) << 4)));
        bfrag av1 = *(const bfrag*)(vT + m1 * 128 + (koff ^ ((m1 & 7) << 4)));
        acc_vs[0] = MFMA(av0, ones, acc_vs[0]);
        acc_vs[1] = MFMA(av1, ones, acc_vs[1]);
      }
      #pragma unroll
      for (int dt = 0; dt < 8; dt += 2){
        int d0 = dt * 16 + lc, d1 = (dt + 1) * 16 + lc;
        bfrag b0 = *(const bfrag*)(vT + d0 * 128 + (koff ^ ((d0 & 7) << 4)));
        bfrag b1 = *(const bfrag*)(vT + d1 * 128 + (koff ^ ((d1 & 7) << 4)));
        acc[0][dt] = MFMA(a0, b0, acc[0][dt]);
        acc[1][dt] = MFMA(a1, b0, acc[1][dt]);
        acc[0][dt + 1] = MFMA(a0, b1, acc[0][dt + 1]);
        acc[1][dt + 1] = MFMA(a1, b1, acc[1][dt + 1]);
      }
    }
  }

  // ---- combine the two token-half partials in-block (th=1 -> th=0) ----
  float* comb = (float*)smem;                     // 32KB scratch (h_t + kT areas)
  float* red2 = (float*)(smem + 49152);           // rowsums: ks [0,128), vs [128,256)
  __syncthreads();                                // all kvs reads done
  if (th == 1){
    #pragma unroll
    for (int mt = 0; mt < 2; ++mt)
      #pragma unroll
      for (int dtl = 0; dtl < 4; ++dtl)
        #pragma unroll
        for (int r = 0; r < 4; ++r)
          comb[(mq * 64 + ln) * 32 + mt * 16 + dtl * 4 + r] = acc[mt][dtl][r];
    if (lc == 0){
      #pragma unroll
      for (int mt = 0; mt < 2; ++mt)
        #pragma unroll
        for (int r = 0; r < 4; ++r){
          int lm = mt * 16 + lg * 4 + r;
          red2[mq * 32 + lm] = acc_ks[mt][r];
          red2[128 + mq * 32 + lm] = acc_vs[mt][r];
        }
    }
  }
  __syncthreads();
  if (th == 0){
    #pragma unroll
    for (int mt = 0; mt < 2; ++mt)
      #pragma unroll
      for (int dtl = 0; dtl < 4; ++dtl)
        #pragma unroll
        for (int r = 0; r < 4; ++r)
          acc[mt][dtl][r] += comb[(mq * 64 + ln) * 32 + mt * 16 + dtl * 4 + r];
    #pragma unroll
    for (int mt = 0; mt < 2; ++mt)
      #pragma unroll
      for (int r = 0; r < 4; ++r){
        int lm = mt * 16 + lg * 4 + r;
        acc_ks[mt][r] += red2[mq * 32 + lm];
        acc_vs[mt][r] += red2[128 + mq * 32 + lm];
      }
  }
  __syncthreads();
  if (th == 1){
    #pragma unroll
    for (int mt = 0; mt < 2; ++mt)
      #pragma unroll
      for (int dtl = 0; dtl < 4; ++dtl)
        #pragma unroll
        for (int r = 0; r < 4; ++r)
          comb[(mq * 64 + ln) * 32 + mt * 16 + dtl * 4 + r] = acc[mt][4 + dtl][r];
  }
  __syncthreads();
  if (th == 0){
    #pragma unroll
    for (int mt = 0; mt < 2; ++mt)
      #pragma unroll
      for (int dtl = 0; dtl < 4; ++dtl)
        #pragma unroll
        for (int r = 0; r < 4; ++r)
          acc[mt][4 + dtl][r] += comb[(mq * 64 + ln) * 32 + mt * 16 + dtl * 4 + r];

    float* op = kvsP + (size_t)blockIdx.x * 16384;
    #pragma unroll
    for (int mt = 0; mt < 2; ++mt)
      #pragma unroll
      for (int dt = 0; dt < 8; ++dt)
        #pragma unroll
        for (int r = 0; r < 4; ++r){
          int m = mq * 32 + mt * 16 + lg * 4 + r;
          int d = dt * 16 + lc;
          op[m * 128 + d] = acc[mt][dt][r];
        }
    if (lc == 0){
      #pragma unroll
      for (int mt = 0; mt < 2; ++mt)
        #pragma unroll
        for (int r = 0; r < 4; ++r){
          int m = mq * 32 + mt * 16 + lg * 4 + r;
          ksvP[(size_t)blockIdx.x * 256 + m] = acc_ks[mt][r];
          ksvP[(size_t)blockIdx.x * 256 + 128 + m] = acc_vs[mt][r];
        }
    }
  }
}

// ---------------- kernel 4: fixed-order reduce of partials ----------------
__global__ __launch_bounds__(256) void reduce_kernel(const float* __restrict__ kvsP, const float* __restrict__ ksvP,
                                                     ushort* __restrict__ kvsT, float* __restrict__ ksum,
                                                     float* __restrict__ vmean){
  int t = blockIdx.x * 256 + threadIdx.x;
  if (t < 65536){
    int h = t >> 14, md = t & 16383;
    const float* p = kvsP + (size_t)h * 16384 + md;
    float s = 0.f;
    for (int c = 0; c < NCHUNK; ++c) s += p[(size_t)c * 65536];
    int m = md >> 7, d = md & 127;
    kvsT[h * 16384 + d * 128 + m] = f2bf(s);      // kvsT[h][d][m]
  } else if (t < 66048){
    int s_ = t - 65536; int h = s_ >> 7, m = s_ & 127;
    const float* p = ksvP + h * 256 + m;
    float s = 0.f;
    for (int c = 0; c < NCHUNK; ++c) s += p[(size_t)c * 1024];
    ksum[s_] = s;
  } else if (t < 66560){
    int s_ = t - 66048; int h = s_ >> 7, d = s_ & 127;
    const float* p = ksvP + h * 256 + 128 + d;
    float s = 0.f;
    for (int c = 0; c < NCHUNK; ++c) s += p[(size_t)c * 1024];
    vmean[s_] = s * (1.0f / FLT_L);
  }
}

// ---------------- kernel 5: wave-per-head q + d-slice num + residual + group-parallel LN ----------------
__global__ __launch_bounds__(256, 2) void attn_kernel(const ushort* __restrict__ hbf, const ushort* __restrict__ wqT,
                                                      const float* __restrict__ bq, const ushort* __restrict__ kvsT,
                                                      const float* __restrict__ ksum, const float* __restrict__ vmean,
                                                      const float* __restrict__ g1, const float* __restrict__ b1,
                                                      float* __restrict__ out){
  __shared__ char smem[81920];
  char* qlds = smem;                               // [64 tok][512 m] bf16 swizzled, 64KB
  ushort* h_t = (ushort*)(smem + 65536);           // [64 tok][128 i] bf16 swizzled, 16KB (dead after B2)
  float* denom_l = (float*)(smem + 65536);         // [4 head][64 tok] (aliases h_t after B2)
  float* scl_l   = (float*)(smem + 66560);         // [4 head][64 tok]
  float* X = (float*)smem;                         // [64 tok][128 d] f32 swizzled, 32KB (aliases qlds after B4)

  int tid = threadIdx.x, wv = tid >> 6, ln = tid & 63;
  int lg = ln >> 4, lc = ln & 15;
  int tok0 = blockIdx.x * 64;

  // stage h tile
  const char* hsrc = (const char*)hbf + (size_t)tok0 * 256;
  #pragma unroll
  for (int p = 0; p < 4; ++p){
    int off = tid * 16 + p * 4096;
    int swz = off ^ (((off >> 8) & 7) << 4);
    *(bfrag*)((char*)h_t + swz) = *(const bfrag*)(hsrc + off);
  }
  __syncthreads();                                 // B1

  f32x4 zero4 = {0.f, 0.f, 0.f, 0.f};

  // ---- q phase: this wave's head = wv; all 128 m, 64 tok; 2 m-halves ----
  float ssv[4] = {0.f, 0.f, 0.f, 0.f}, qdv[4] = {0.f, 0.f, 0.f, 0.f};
  for (int mh = 0; mh < 2; ++mh){
    f32x4 acc[4][4];
    #pragma unroll
    for (int a = 0; a < 4; ++a)
      #pragma unroll
      for (int b = 0; b < 4; ++b) acc[a][b] = zero4;
    const ushort* WQ = wqT + (size_t)(wv * 128 + mh * 64 + lc) * 128 + lg * 8;
    #pragma unroll
    for (int ks = 0; ks < 4; ++ks){
      bfrag bb[4];
      #pragma unroll
      for (int nt = 0; nt < 4; ++nt){
        int tok = nt * 16 + lc;
        bb[nt] = *(const bfrag*)((char*)h_t + tok * 256 + ((ks * 64 + lg * 16) ^ ((tok & 7) << 4)));
      }
      #pragma unroll
      for (int mt = 0; mt < 4; ++mt){
        bfrag af = *(const bfrag*)(WQ + mt * 2048 + ks * 32);
        #pragma unroll
        for (int nt = 0; nt < 4; ++nt) acc[mt][nt] = MFMA(af, bb[nt], acc[mt][nt]);
      }
    }
    // bias + stats + packed unscaled bf16 write to qlds (ds_write_b64)
    #pragma unroll
    for (int mt = 0; mt < 4; ++mt){
      int mb = wv * 128 + mh * 64 + mt * 16 + lg * 4;
      float4_t bq4 = *(const float4_t*)(bq + mb);
      float4_t ks4 = *(const float4_t*)(ksum + mb);
      #pragma unroll
      for (int nt = 0; nt < 4; ++nt){
        int tok = nt * 16 + lc;
        int sw = (tok & 7) << 4;
        short4_t pk;
        #pragma unroll
        for (int r = 0; r < 4; ++r){
          float val = acc[mt][nt][r] + bq4[r];
          ssv[nt] += val * val;
          qdv[nt] += val * ks4[r];
          pk[r] = (short)f2bf(val);
        }
        *(short4_t*)(qlds + tok * 1024 + ((mb * 2) ^ sw)) = pk;   // 8B aligned; XOR hits bits 4-6 only
      }
    }
  }
  #pragma unroll
  for (int nt = 0; nt < 4; ++nt){
    ssv[nt] += __shfl_xor(ssv[nt], 16); ssv[nt] += __shfl_xor(ssv[nt], 32);
    qdv[nt] += __shfl_xor(qdv[nt], 16); qdv[nt] += __shfl_xor(qdv[nt], 32);
  }
  float scl[4], dnm[4];
  #pragma unroll
  for (int nt = 0; nt < 4; ++nt){
    scl[nt] = 1.f / (sqrtf(ssv[nt]) + 1e-8f);
    dnm[nt] = qdv[nt] * scl[nt] + FLT_L;
  }
  // capture residual h to registers while h_t is still alive
  short4_t hres[2][4];
  #pragma unroll
  for (int dt = 0; dt < 2; ++dt)
    #pragma unroll
    for (int nt = 0; nt < 4; ++nt){
      int tok = nt * 16 + lc;
      int d0 = wv * 32 + dt * 16 + lg * 4;
      hres[dt][nt] = *(const short4_t*)((char*)h_t + tok * 256 + ((d0 * 2) ^ ((tok & 7) << 4)));
    }
  __syncthreads();                                 // B2: qhat visible, h_t dead
  denom_l[wv * 64 + lg * 16 + lc] = dnm[lg];
  scl_l[wv * 64 + lg * 16 + lc] = scl[lg];
  __syncthreads();                                 // B3: denom/scl visible

  // ---- num phase: this wave's d-slice = [wv*32, wv*32+32) across ALL heads ----
  f32x4 macc[2][4];
  #pragma unroll
  for (int a = 0; a < 2; ++a)
    #pragma unroll
    for (int b = 0; b < 4; ++b) macc[a][b] = zero4;
  #pragma unroll
  for (int hd = 0; hd < 4; ++hd){
    f32x4 an[2][4];
    #pragma unroll
    for (int a = 0; a < 2; ++a)
      #pragma unroll
      for (int b = 0; b < 4; ++b) an[a][b] = zero4;
    const ushort* KV = kvsT + (size_t)(hd * 128 + wv * 32 + lc) * 128 + lg * 8;
    #pragma unroll
    for (int ks2 = 0; ks2 < 4; ++ks2){
      bfrag bb[4];
      #pragma unroll
      for (int nt = 0; nt < 4; ++nt){
        int tok = nt * 16 + lc;
        int m = hd * 128 + ks2 * 32 + lg * 8;
        bb[nt] = *(const bfrag*)(qlds + tok * 1024 + ((m * 2) ^ ((tok & 7) << 4)));
      }
      bfrag a0 = *(const bfrag*)(KV + ks2 * 32);
      bfrag a1 = *(const bfrag*)(KV + 2048 + ks2 * 32);
      #pragma unroll
      for (int nt = 0; nt < 4; ++nt){
        an[0][nt] = MFMA(a0, bb[nt], an[0][nt]);
        an[1][nt] = MFMA(a1, bb[nt], an[1][nt]);
      }
    }
    float4_t vm4[2];
    #pragma unroll
    for (int dt = 0; dt < 2; ++dt)
      vm4[dt] = *(const float4_t*)(vmean + hd * 128 + wv * 32 + dt * 16 + lg * 4);
    #pragma unroll
    for (int nt = 0; nt < 4; ++nt){
      float f2 = 0.25f / (denom_l[hd * 64 + nt * 16 + lc] + 1e-8f);
      float f1 = scl_l[hd * 64 + nt * 16 + lc] * f2;
      #pragma unroll
      for (int dt = 0; dt < 2; ++dt)
        #pragma unroll
        for (int r = 0; r < 4; ++r)
          macc[dt][nt][r] += an[dt][nt][r] * f1 + vm4[dt][r] * f2;
    }
  }
  __syncthreads();                                 // B4: qlds reads done -> X may alias
  #pragma unroll
  for (int dt = 0; dt < 2; ++dt)
    #pragma unroll
    for (int nt = 0; nt < 4; ++nt){
      int tok = nt * 16 + lc;
      int d0 = wv * 32 + dt * 16 + lg * 4;
      float4_t ox;
      #pragma unroll
      for (int r = 0; r < 4; ++r)
        ox[r] = 0.5f * macc[dt][nt][r] + 0.5f * bf2f((ushort)hres[dt][nt][r]);
      *(float4_t*)((char*)X + tok * 512 + ((d0 * 4) ^ ((tok & 7) << 4))) = ox;  // 16B aligned b128 store
    }
  __syncthreads();                                 // B5: X ready

  // ---- group-parallel LN: each 16-lane group owns one token; lane holds 8 channels ----
  float g1v[8], b1v[8];
  {
    float4_t ga = *(const float4_t*)(g1 + lc * 8);
    float4_t gb = *(const float4_t*)(g1 + lc * 8 + 4);
    float4_t ba = *(const float4_t*)(b1 + lc * 8);
    float4_t bb = *(const float4_t*)(b1 + lc * 8 + 4);
    #pragma unroll
    for (int j = 0; j < 4; ++j){ g1v[j] = ga[j]; g1v[j + 4] = gb[j]; b1v[j] = ba[j]; b1v[j + 4] = bb[j]; }
  }
  for (int it = 0; it < 4; ++it){
    int tokl = wv * 16 + it * 4 + lg;
    int sw = (tokl & 7) << 4;
    float4_t xa = *(const float4_t*)((char*)X + tokl * 512 + ((lc * 32) ^ sw));
    float4_t xb = *(const float4_t*)((char*)X + tokl * 512 + ((lc * 32 + 16) ^ sw));
    float s = ((xa[0] + xa[1]) + (xa[2] + xa[3])) + ((xb[0] + xb[1]) + (xb[2] + xb[3]));
    s += __shfl_xor(s, 1); s += __shfl_xor(s, 2);
    s += __shfl_xor(s, 4); s += __shfl_xor(s, 8);
    float mean = s * 0.0078125f;
    float ssq = 0.f;
    #pragma unroll
    for (int j = 0; j < 4; ++j){
      float da = xa[j] - mean, db = xb[j] - mean;
      ssq += da * da + db * db;
    }
    ssq += __shfl_xor(ssq, 1); ssq += __shfl_xor(ssq, 2);
    ssq += __shfl_xor(ssq, 4); ssq += __shfl_xor(ssq, 8);
    float rstd = rsqrtf(ssq * 0.0078125f + 1e-5f);
    float4_t oa, ob;
    #pragma unroll
    for (int j = 0; j < 4; ++j){
      oa[j] = fmaf((xa[j] - mean) * rstd, g1v[j], b1v[j]);
      ob[j] = fmaf((xb[j] - mean) * rstd, g1v[j + 4], b1v[j + 4]);
    }
    size_t gtok = (size_t)tok0 + tokl;
    *(float4_t*)(out + gtok * 128 + lc * 8) = oa;
    *(float4_t*)(out + gtok * 128 + lc * 8 + 4) = ob;
  }
}

extern "C" void kernel_launch(void* const* d_in, const int* in_sizes, int n_in,
                              void* d_out, int out_size, void* d_ws, size_t ws_size,
                              hipStream_t stream){
  (void)in_sizes; (void)n_in; (void)out_size; (void)ws_size;
  const float* x    = (const float*)d_in[0];
  const float* fc0w = (const float*)d_in[1];
  const float* fc0b = (const float*)d_in[2];
  const float* ln0g = (const float*)d_in[3];
  const float* ln0b = (const float*)d_in[4];
  const float* wqw  = (const float*)d_in[5];
  const float* wqb  = (const float*)d_in[6];
  const float* wkw  = (const float*)d_in[7];
  const float* wkb  = (const float*)d_in[8];
  const float* wvw  = (const float*)d_in[9];
  const float* wvb  = (const float*)d_in[10];
  const float* ln1g = (const float*)d_in[11];
  const float* ln1b = (const float*)d_in[12];
  float* out = (float*)d_out;
  char* ws = (char*)d_ws;

  ushort* hbf   = (ushort*)(ws);                                  // LPAD*128 bf16 = 43,515,904 B
  ushort* wqT   = (ushort*)(ws + 43515904);                       // 131072 B
  ushort* wkT   = (ushort*)(ws + 43515904 + 131072);
  ushort* wvT   = (ushort*)(ws + 43515904 + 262144);
  ushort* kvsT  = (ushort*)(ws + 43515904 + 393216);              // 131072 B
  float*  ksum  = (float*)(ws + 43515904 + 524288);               // 2048 B
  float*  vmean = (float*)(ws + 43515904 + 526336);               // 2048 B
  float*  kvsP  = (float*)(ws + 43515904 + 528384);               // 166*4*16384*4 = 43,515,904 B
  float*  ksvP  = (float*)(ws + 43515904 + 528384 + 43515904);    // 166*4*256*4 = 679,936 B

  hipLaunchKernelGGL(prep_w_kernel, dim3(768), dim3(256), 0, stream, wqw, wkw, wvw, wqT, wkT, wvT);
  hipLaunchKernelGGL(fc0_kernel, dim3(5312), dim3(256), 0, stream, x, fc0w, fc0b, ln0g, ln0b, hbf);
  hipLaunchKernelGGL(kv_kernel, dim3(664), dim3(512), 0, stream, hbf, wkT, wvT, wkb, wvb, kvsP, ksvP);
  hipLaunchKernelGGL(reduce_kernel, dim3(260), dim3(256), 0, stream, kvsP, ksvP, kvsT, ksum, vmean);
  hipLaunchKernelGGL(attn_kernel, dim3(2649), dim3(256), 0, stream, hbf, wqT, wqb, kvsT, ksum, vmean, ln1g, ln1b, out);
}

// Round 16
// 374.389 us; speedup vs baseline: 1.0018x; 1.0018x over previous
//
#include <hip/hip_runtime.h>

#define L_TOK   169536
#define LPAD    169984
#define NCHUNK  166
#define FLT_L   169536.0f

typedef __attribute__((ext_vector_type(8))) short bfrag;
typedef __attribute__((ext_vector_type(4))) short short4_t;
typedef __attribute__((ext_vector_type(4))) float f32x4;
typedef __attribute__((ext_vector_type(4))) float float4_t;

__device__ __forceinline__ ushort f2bf(float f){
  unsigned u = __float_as_uint(f);
  u += 0x7fffu + ((u >> 16) & 1u);
  return (ushort)(u >> 16);
}
__device__ __forceinline__ float bf2f(ushort h){ return __uint_as_float(((unsigned)h) << 16); }

__device__ __forceinline__ f32x4 MFMA(bfrag a, bfrag b, f32x4 c){
  return __builtin_amdgcn_mfma_f32_16x16x32_bf16(a, b, c, 0, 0, 0);
}

// ---------------- kernel 1: transpose weights to bf16 [512][128] ----------------
__global__ __launch_bounds__(256) void prep_w_kernel(const float* __restrict__ wq, const float* __restrict__ wk,
                                                     const float* __restrict__ wv, ushort* __restrict__ wqT,
                                                     ushort* __restrict__ wkT, ushort* __restrict__ wvT){
  int t = blockIdx.x * 256 + threadIdx.x;        // 3*65536 threads
  int mat = t >> 16;
  int idx = t & 65535;
  int n = idx >> 7, i = idx & 127;
  const float* w = (mat == 0) ? wq : (mat == 1) ? wk : wv;
  ushort* o = (mat == 0) ? wqT : (mat == 1) ? wkT : wvT;
  o[idx] = f2bf(w[i * 512 + n]);                 // WT[n][i] = W[i][n]
}

// ---------------- kernel 2: h = relu(LN(x @ fc0_w + b)) -> bf16 [LPAD][128] ----------------
__global__ __launch_bounds__(256) void fc0_kernel(const float* __restrict__ x, const float* __restrict__ w,
                                                  const float* __restrict__ bias, const float* __restrict__ g,
                                                  const float* __restrict__ be, ushort* __restrict__ hbf){
  __shared__ float wl[8192];                      // [64 k][128 ch] fp32, 32KB
  __shared__ float xs[2048];                      // [32 tok][64 k] fp32, 8KB
  int tid = threadIdx.x;
  #pragma unroll
  for (int j = 0; j < 8; ++j) ((float4_t*)wl)[tid + j * 256] = ((const float4_t*)w)[tid + j * 256];
  int tok0 = blockIdx.x * 32;                     // L_TOK % 32 == 0: blocks fully valid or fully invalid
  bool blk_valid = (tok0 + 32) <= L_TOK;
  if (blk_valid){
    const float4_t* xsrc = (const float4_t*)(x + (size_t)tok0 * 64);
    ((float4_t*)xs)[tid] = xsrc[tid];
    ((float4_t*)xs)[tid + 256] = xsrc[tid + 256];
  }
  __syncthreads();
  int wv = tid >> 6, ln = tid & 63;
  if (!blk_valid){
    for (int t = 0; t < 8; ++t){
      size_t tok = (size_t)tok0 + wv * 8 + t;
      hbf[tok * 128 + ln] = 0; hbf[tok * 128 + ln + 64] = 0;
    }
    return;
  }
  float b0 = bias[ln], b1 = bias[ln + 64];
  float g0 = g[ln], g1v = g[ln + 64], e0 = be[ln], e1 = be[ln + 64];
  for (int t = 0; t < 8; ++t){
    int tokl = wv * 8 + t;
    float a0 = b0, a1 = b1;
    #pragma unroll
    for (int i4 = 0; i4 < 16; ++i4){
      float4_t xv = *(const float4_t*)(xs + tokl * 64 + i4 * 4);  // wave-uniform -> LDS broadcast
      #pragma unroll
      for (int u = 0; u < 4; ++u){
        a0 = fmaf(xv[u], wl[(i4 * 4 + u) * 128 + ln], a0);
        a1 = fmaf(xv[u], wl[(i4 * 4 + u) * 128 + ln + 64], a1);
      }
    }
    float s = a0 + a1;
    #pragma unroll
    for (int m = 1; m < 64; m <<= 1) s += __shfl_xor(s, m);
    float mean = s * 0.0078125f;
    float d0 = a0 - mean, d1 = a1 - mean;
    float ss = d0 * d0 + d1 * d1;
    #pragma unroll
    for (int m = 1; m < 64; m <<= 1) ss += __shfl_xor(ss, m);
    float rstd = rsqrtf(ss * 0.0078125f + 1e-5f);
    float y0 = fmaxf(fmaf(d0 * rstd, g0, e0), 0.f);
    float y1 = fmaxf(fmaf(d1 * rstd, g1v, e1), 0.f);
    size_t tok = (size_t)tok0 + tokl;
    hbf[tok * 128 + ln] = f2bf(y0);
    hbf[tok * 128 + ln + 64] = f2bf(y1);
  }
}

// ---------------- kernel 3: 8-wave token-split (chunk, head) kv kernel, uncapped VGPR ----------------
__global__ __launch_bounds__(512, 1) void kv_kernel(const ushort* __restrict__ hbf, const ushort* __restrict__ wkT,
                                                    const ushort* __restrict__ wvT, const float* __restrict__ bk,
                                                    const float* __restrict__ bv, float* __restrict__ kvsP,
                                                    float* __restrict__ ksvP){
  __shared__ char smem[51200];
  ushort* h_t = (ushort*)smem;                    // [64 tok][128 i] bf16, swizzled, 16KB
  char* kT = smem + 16384;                        // [128 m][64 tok] bf16, swizzled, 16KB
  char* vT = smem + 32768;                        // [128 d][64 tok]
  float* red = (float*)(smem + 49152);            // [64 tok][4 mq] f32, 1KB (+1KB spare)
  int tid = threadIdx.x, w = tid >> 6, ln = tid & 63;
  int mq = w & 3, th = w >> 2;
  int head = blockIdx.x & 3, chunk = blockIdx.x >> 2;
  int lg = ln >> 4, lc = ln & 15;

  f32x4 zero4 = {0.f, 0.f, 0.f, 0.f};
  f32x4 acc[2][8];                                // kvs partial over this wave's token half
  #pragma unroll
  for (int a = 0; a < 2; ++a)
    #pragma unroll
    for (int b = 0; b < 8; ++b) acc[a][b] = zero4;
  f32x4 acc_ks[2] = {zero4, zero4}, acc_vs[2] = {zero4, zero4};

  bfrag ones;
  #pragma unroll
  for (int j = 0; j < 8; ++j) ones[j] = (short)0x3F80;   // bf16 1.0

  const ushort* WK = wkT + (size_t)(head * 128 + mq * 32 + lc) * 128 + lg * 8;
  const ushort* WV = wvT + (size_t)(head * 128 + mq * 32 + lc) * 128 + lg * 8;
  const float* BK = bk + head * 128 + mq * 32 + lg * 4;
  const float* BV = bv + head * 128 + mq * 32 + lg * 4;

  // prologue: stage tile 0 (16KB) into registers (512 thr x 32B)
  bfrag st[2];
  {
    const char* h0 = (const char*)hbf + (size_t)chunk * 1024 * 256;
    #pragma unroll
    for (int p = 0; p < 2; ++p) st[p] = *(const bfrag*)(h0 + tid * 16 + p * 8192);
  }

  for (int it = 0; it < 16; ++it){
    #pragma unroll
    for (int p = 0; p < 2; ++p){
      int off = tid * 16 + p * 8192;
      int swz = off ^ (((off >> 8) & 7) << 4);
      *(bfrag*)((char*)h_t + swz) = st[p];
    }
    __syncthreads();                              // S1: h_t ready
    if (it < 15){
      const char* hn = (const char*)hbf + ((size_t)chunk * 1024 + (it + 1) * 64) * 256;
      #pragma unroll
      for (int p = 0; p < 2; ++p) st[p] = *(const bfrag*)(hn + tid * 16 + p * 8192);
    }
    int tok0 = chunk * 1024 + it * 64;

    // ---- k GEMM: m-tile [mq*32, +32), tokens [th*32, +32): 16 MFMA ----
    f32x4 ak[2][2];
    #pragma unroll
    for (int a = 0; a < 2; ++a)
      #pragma unroll
      for (int b = 0; b < 2; ++b) ak[a][b] = zero4;
    #pragma unroll
    for (int ks = 0; ks < 4; ++ks){
      bfrag wk0 = *(const bfrag*)(WK + ks * 32);
      bfrag wk1 = *(const bfrag*)(WK + 2048 + ks * 32);
      #pragma unroll
      for (int nt = 0; nt < 2; ++nt){
        int tok = th * 32 + nt * 16 + lc;
        bfrag bb = *(const bfrag*)((char*)h_t + tok * 256 + ((ks * 64 + lg * 16) ^ ((tok & 7) << 4)));
        ak[0][nt] = MFMA(wk0, bb, ak[0][nt]);
        ak[1][nt] = MFMA(wk1, bb, ak[1][nt]);
      }
    }
    // bias (reloaded per use, loop-invariant addr -> L1 hit) + tail-mask + sum-of-squares
    float ss[2];
    {
      float4_t bk0 = *(const float4_t*)(BK);
      float4_t bk1 = *(const float4_t*)(BK + 16);
      #pragma unroll
      for (int nt = 0; nt < 2; ++nt){
        int gtok = tok0 + th * 32 + nt * 16 + lc;
        bool valid = gtok < L_TOK;
        ss[nt] = 0.f;
        #pragma unroll
        for (int r = 0; r < 4; ++r){
          float k0 = valid ? ak[0][nt][r] + bk0[r] : 0.f;
          float k1 = valid ? ak[1][nt][r] + bk1[r] : 0.f;
          ak[0][nt][r] = k0; ak[1][nt][r] = k1;
          ss[nt] += k0 * k0 + k1 * k1;
        }
        ss[nt] += __shfl_xor(ss[nt], 16);
        ss[nt] += __shfl_xor(ss[nt], 32);
      }
    }
    if (ln < 16){
      #pragma unroll
      for (int nt = 0; nt < 2; ++nt) red[(th * 32 + nt * 16 + ln) * 4 + mq] = ss[nt];
    }
    __syncthreads();                              // S2: red ready (each half written by its 4 mq waves)
    float scale[2];
    #pragma unroll
    for (int nt = 0; nt < 2; ++nt){
      float4_t s4 = *(const float4_t*)(red + (th * 32 + nt * 16 + lc) * 4);
      scale[nt] = 1.f / (sqrtf((s4[0] + s4[1]) + (s4[2] + s4[3])) + 1e-8f);
    }
    // write k-hat quadrant
    #pragma unroll
    for (int mt = 0; mt < 2; ++mt)
      #pragma unroll
      for (int r = 0; r < 4; ++r){
        int m = mq * 32 + mt * 16 + lg * 4 + r;
        int sw = (m & 7) << 4;
        #pragma unroll
        for (int nt = 0; nt < 2; ++nt){
          int col = th * 32 + nt * 16 + lc;
          *(ushort*)(kT + m * 128 + ((col * 2) ^ sw)) = f2bf(ak[mt][nt][r] * scale[nt]);
        }
      }

    // ---- v GEMM (reuse ak registers) ----
    #pragma unroll
    for (int a = 0; a < 2; ++a)
      #pragma unroll
      for (int b = 0; b < 2; ++b) ak[a][b] = zero4;
    #pragma unroll
    for (int ks = 0; ks < 4; ++ks){
      bfrag wv0 = *(const bfrag*)(WV + ks * 32);
      bfrag wv1 = *(const bfrag*)(WV + 2048 + ks * 32);
      #pragma unroll
      for (int nt = 0; nt < 2; ++nt){
        int tok = th * 32 + nt * 16 + lc;
        bfrag bb = *(const bfrag*)((char*)h_t + tok * 256 + ((ks * 64 + lg * 16) ^ ((tok & 7) << 4)));
        ak[0][nt] = MFMA(wv0, bb, ak[0][nt]);
        ak[1][nt] = MFMA(wv1, bb, ak[1][nt]);
      }
    }
    {
      float4_t bv0 = *(const float4_t*)(BV);
      float4_t bv1 = *(const float4_t*)(BV + 16);
      #pragma unroll
      for (int nt = 0; nt < 2; ++nt){
        int gtok = tok0 + th * 32 + nt * 16 + lc;
        bool valid = gtok < L_TOK;
        int col = th * 32 + nt * 16 + lc;
        #pragma unroll
        for (int r = 0; r < 4; ++r){
          float v0 = valid ? ak[0][nt][r] + bv0[r] : 0.f;
          float v1 = valid ? ak[1][nt][r] + bv1[r] : 0.f;
          int m0_ = mq * 32 + lg * 4 + r;
          int m1_ = m0_ + 16;
          *(ushort*)(vT + m0_ * 128 + ((col * 2) ^ ((m0_ & 7) << 4))) = f2bf(v0);
          *(ushort*)(vT + m1_ * 128 + ((col * 2) ^ ((m1_ & 7) << 4))) = f2bf(v1);
        }
      }
    }
    __syncthreads();                              // S3: kT/vT ready

    // ---- kvs over this wave's K-window (32 tokens): chunked B-loads to cap liveness ----
    {
      int koff = th * 64 + lg * 16;
      int m0 = mq * 32 + lc, m1 = m0 + 16;
      bfrag a0 = *(const bfrag*)(kT + m0 * 128 + (koff ^ ((m0 & 7) << 4)));
      bfrag a1 = *(const bfrag*)(kT + m1 * 128 + (koff ^ ((m1 & 7) << 4)));
      acc_ks[0] = MFMA(a0, ones, acc_ks[0]);
      acc_ks[1] = MFMA(a1, ones, acc_ks[1]);
      {
        bfrag av0 = *(const bfrag*)(vT + m0 * 128 + (koff ^ ((m0 & 7) << 4)));
        bfrag av1 = *(const bfrag*)(vT + m1 * 128 + (koff ^ ((m1 & 7) << 4)));
        acc_vs[0] = MFMA(av0, ones, acc_vs[0]);
        acc_vs[1] = MFMA(av1, ones, acc_vs[1]);
      }
      #pragma unroll
      for (int dt = 0; dt < 8; dt += 2){
        int d0 = dt * 16 + lc, d1 = (dt + 1) * 16 + lc;
        bfrag b0 = *(const bfrag*)(vT + d0 * 128 + (koff ^ ((d0 & 7) << 4)));
        bfrag b1 = *(const bfrag*)(vT + d1 * 128 + (koff ^ ((d1 & 7) << 4)));
        acc[0][dt] = MFMA(a0, b0, acc[0][dt]);
        acc[1][dt] = MFMA(a1, b0, acc[1][dt]);
        acc[0][dt + 1] = MFMA(a0, b1, acc[0][dt + 1]);
        acc[1][dt + 1] = MFMA(a1, b1, acc[1][dt + 1]);
      }
    }
  }

  // ---- combine the two token-half partials in-block (th=1 -> th=0) ----
  float* comb = (float*)smem;                     // 32KB scratch (h_t + kT areas)
  float* red2 = (float*)(smem + 49152);           // rowsums: ks [0,128), vs [128,256)
  __syncthreads();                                // all kvs reads done
  if (th == 1){
    #pragma unroll
    for (int mt = 0; mt < 2; ++mt)
      #pragma unroll
      for (int dtl = 0; dtl < 4; ++dtl)
        #pragma unroll
        for (int r = 0; r < 4; ++r)
          comb[(mq * 64 + ln) * 32 + mt * 16 + dtl * 4 + r] = acc[mt][dtl][r];
    if (lc == 0){
      #pragma unroll
      for (int mt = 0; mt < 2; ++mt)
        #pragma unroll
        for (int r = 0; r < 4; ++r){
          int lm = mt * 16 + lg * 4 + r;
          red2[mq * 32 + lm] = acc_ks[mt][r];
          red2[128 + mq * 32 + lm] = acc_vs[mt][r];
        }
    }
  }
  __syncthreads();
  if (th == 0){
    #pragma unroll
    for (int mt = 0; mt < 2; ++mt)
      #pragma unroll
      for (int dtl = 0; dtl < 4; ++dtl)
        #pragma unroll
        for (int r = 0; r < 4; ++r)
          acc[mt][dtl][r] += comb[(mq * 64 + ln) * 32 + mt * 16 + dtl * 4 + r];
    #pragma unroll
    for (int mt = 0; mt < 2; ++mt)
      #pragma unroll
      for (int r = 0; r < 4; ++r){
        int lm = mt * 16 + lg * 4 + r;
        acc_ks[mt][r] += red2[mq * 32 + lm];
        acc_vs[mt][r] += red2[128 + mq * 32 + lm];
      }
  }
  __syncthreads();
  if (th == 1){
    #pragma unroll
    for (int mt = 0; mt < 2; ++mt)
      #pragma unroll
      for (int dtl = 0; dtl < 4; ++dtl)
        #pragma unroll
        for (int r = 0; r < 4; ++r)
          comb[(mq * 64 + ln) * 32 + mt * 16 + dtl * 4 + r] = acc[mt][4 + dtl][r];
  }
  __syncthreads();
  if (th == 0){
    #pragma unroll
    for (int mt = 0; mt < 2; ++mt)
      #pragma unroll
      for (int dtl = 0; dtl < 4; ++dtl)
        #pragma unroll
        for (int r = 0; r < 4; ++r)
          acc[mt][4 + dtl][r] += comb[(mq * 64 + ln) * 32 + mt * 16 + dtl * 4 + r];

    float* op = kvsP + (size_t)blockIdx.x * 16384;
    #pragma unroll
    for (int mt = 0; mt < 2; ++mt)
      #pragma unroll
      for (int dt = 0; dt < 8; ++dt)
        #pragma unroll
        for (int r = 0; r < 4; ++r){
          int m = mq * 32 + mt * 16 + lg * 4 + r;
          int d = dt * 16 + lc;
          op[m * 128 + d] = acc[mt][dt][r];
        }
    if (lc == 0){
      #pragma unroll
      for (int mt = 0; mt < 2; ++mt)
        #pragma unroll
        for (int r = 0; r < 4; ++r){
          int m = mq * 32 + mt * 16 + lg * 4 + r;
          ksvP[(size_t)blockIdx.x * 256 + m] = acc_ks[mt][r];
          ksvP[(size_t)blockIdx.x * 256 + 128 + m] = acc_vs[mt][r];
        }
    }
  }
}

// ---------------- kernel 4: fixed-order reduce of partials ----------------
__global__ __launch_bounds__(256) void reduce_kernel(const float* __restrict__ kvsP, const float* __restrict__ ksvP,
                                                     ushort* __restrict__ kvsT, float* __restrict__ ksum,
                                                     float* __restrict__ vmean){
  int t = blockIdx.x * 256 + threadIdx.x;
  if (t < 65536){
    int h = t >> 14, md = t & 16383;
    const float* p = kvsP + (size_t)h * 16384 + md;
    float s = 0.f;
    for (int c = 0; c < NCHUNK; ++c) s += p[(size_t)c * 65536];
    int m = md >> 7, d = md & 127;
    kvsT[h * 16384 + d * 128 + m] = f2bf(s);      // kvsT[h][d][m]
  } else if (t < 66048){
    int s_ = t - 65536; int h = s_ >> 7, m = s_ & 127;
    const float* p = ksvP + h * 256 + m;
    float s = 0.f;
    for (int c = 0; c < NCHUNK; ++c) s += p[(size_t)c * 1024];
    ksum[s_] = s;
  } else if (t < 66560){
    int s_ = t - 66048; int h = s_ >> 7, d = s_ & 127;
    const float* p = ksvP + h * 256 + 128 + d;
    float s = 0.f;
    for (int c = 0; c < NCHUNK; ++c) s += p[(size_t)c * 1024];
    vmean[s_] = s * (1.0f / FLT_L);
  }
}

// ---------------- kernel 5: wave-per-head q + d-slice num + residual + group-parallel LN ----------------
__global__ __launch_bounds__(256, 2) void attn_kernel(const ushort* __restrict__ hbf, const ushort* __restrict__ wqT,
                                                      const float* __restrict__ bq, const ushort* __restrict__ kvsT,
                                                      const float* __restrict__ ksum, const float* __restrict__ vmean,
                                                      const float* __restrict__ g1, const float* __restrict__ b1,
                                                      float* __restrict__ out){
  __shared__ char smem[81920];
  char* qlds = smem;                               // [64 tok][512 m] bf16 swizzled, 64KB
  ushort* h_t = (ushort*)(smem + 65536);           // [64 tok][128 i] bf16 swizzled, 16KB (dead after B2)
  float* denom_l = (float*)(smem + 65536);         // [4 head][64 tok] (aliases h_t after B2)
  float* scl_l   = (float*)(smem + 66560);         // [4 head][64 tok]
  float* X = (float*)smem;                         // [64 tok][128 d] f32 swizzled, 32KB (aliases qlds after B4)

  int tid = threadIdx.x, wv = tid >> 6, ln = tid & 63;
  int lg = ln >> 4, lc = ln & 15;
  int tok0 = blockIdx.x * 64;

  // stage h tile
  const char* hsrc = (const char*)hbf + (size_t)tok0 * 256;
  #pragma unroll
  for (int p = 0; p < 4; ++p){
    int off = tid * 16 + p * 4096;
    int swz = off ^ (((off >> 8) & 7) << 4);
    *(bfrag*)((char*)h_t + swz) = *(const bfrag*)(hsrc + off);
  }
  __syncthreads();                                 // B1

  f32x4 zero4 = {0.f, 0.f, 0.f, 0.f};

  // ---- q phase: this wave's head = wv; all 128 m, 64 tok; 2 m-halves ----
  float ssv[4] = {0.f, 0.f, 0.f, 0.f}, qdv[4] = {0.f, 0.f, 0.f, 0.f};
  for (int mh = 0; mh < 2; ++mh){
    f32x4 acc[4][4];
    #pragma unroll
    for (int a = 0; a < 4; ++a)
      #pragma unroll
      for (int b = 0; b < 4; ++b) acc[a][b] = zero4;
    const ushort* WQ = wqT + (size_t)(wv * 128 + mh * 64 + lc) * 128 + lg * 8;
    #pragma unroll
    for (int ks = 0; ks < 4; ++ks){
      bfrag bb[4];
      #pragma unroll
      for (int nt = 0; nt < 4; ++nt){
        int tok = nt * 16 + lc;
        bb[nt] = *(const bfrag*)((char*)h_t + tok * 256 + ((ks * 64 + lg * 16) ^ ((tok & 7) << 4)));
      }
      #pragma unroll
      for (int mt = 0; mt < 4; ++mt){
        bfrag af = *(const bfrag*)(WQ + mt * 2048 + ks * 32);
        #pragma unroll
        for (int nt = 0; nt < 4; ++nt) acc[mt][nt] = MFMA(af, bb[nt], acc[mt][nt]);
      }
    }
    // bias + stats + packed unscaled bf16 write to qlds (ds_write_b64)
    #pragma unroll
    for (int mt = 0; mt < 4; ++mt){
      int mb = wv * 128 + mh * 64 + mt * 16 + lg * 4;
      float4_t bq4 = *(const float4_t*)(bq + mb);
      float4_t ks4 = *(const float4_t*)(ksum + mb);
      #pragma unroll
      for (int nt = 0; nt < 4; ++nt){
        int tok = nt * 16 + lc;
        int sw = (tok & 7) << 4;
        short4_t pk;
        #pragma unroll
        for (int r = 0; r < 4; ++r){
          float val = acc[mt][nt][r] + bq4[r];
          ssv[nt] += val * val;
          qdv[nt] += val * ks4[r];
          pk[r] = (short)f2bf(val);
        }
        *(short4_t*)(qlds + tok * 1024 + ((mb * 2) ^ sw)) = pk;   // 8B aligned; XOR hits bits 4-6 only
      }
    }
  }
  #pragma unroll
  for (int nt = 0; nt < 4; ++nt){
    ssv[nt] += __shfl_xor(ssv[nt], 16); ssv[nt] += __shfl_xor(ssv[nt], 32);
    qdv[nt] += __shfl_xor(qdv[nt], 16); qdv[nt] += __shfl_xor(qdv[nt], 32);
  }
  float scl[4], dnm[4];
  #pragma unroll
  for (int nt = 0; nt < 4; ++nt){
    scl[nt] = 1.f / (sqrtf(ssv[nt]) + 1e-8f);
    dnm[nt] = qdv[nt] * scl[nt] + FLT_L;
  }
  // capture residual h to registers while h_t is still alive
  short4_t hres[2][4];
  #pragma unroll
  for (int dt = 0; dt < 2; ++dt)
    #pragma unroll
    for (int nt = 0; nt < 4; ++nt){
      int tok = nt * 16 + lc;
      int d0 = wv * 32 + dt * 16 + lg * 4;
      hres[dt][nt] = *(const short4_t*)((char*)h_t + tok * 256 + ((d0 * 2) ^ ((tok & 7) << 4)));
    }
  __syncthreads();                                 // B2: qhat visible, h_t dead
  denom_l[wv * 64 + lg * 16 + lc] = dnm[lg];
  scl_l[wv * 64 + lg * 16 + lc] = scl[lg];
  __syncthreads();                                 // B3: denom/scl visible

  // ---- num phase: this wave's d-slice = [wv*32, wv*32+32) across ALL heads ----
  f32x4 macc[2][4];
  #pragma unroll
  for (int a = 0; a < 2; ++a)
    #pragma unroll
    for (int b = 0; b < 4; ++b) macc[a][b] = zero4;
  #pragma unroll
  for (int hd = 0; hd < 4; ++hd){
    f32x4 an[2][4];
    #pragma unroll
    for (int a = 0; a < 2; ++a)
      #pragma unroll
      for (int b = 0; b < 4; ++b) an[a][b] = zero4;
    const ushort* KV = kvsT + (size_t)(hd * 128 + wv * 32 + lc) * 128 + lg * 8;
    #pragma unroll
    for (int ks2 = 0; ks2 < 4; ++ks2){
      bfrag bb[4];
      #pragma unroll
      for (int nt = 0; nt < 4; ++nt){
        int tok = nt * 16 + lc;
        int m = hd * 128 + ks2 * 32 + lg * 8;
        bb[nt] = *(const bfrag*)(qlds + tok * 1024 + ((m * 2) ^ ((tok & 7) << 4)));
      }
      bfrag a0 = *(const bfrag*)(KV + ks2 * 32);
      bfrag a1 = *(const bfrag*)(KV + 2048 + ks2 * 32);
      #pragma unroll
      for (int nt = 0; nt < 4; ++nt){
        an[0][nt] = MFMA(a0, bb[nt], an[0][nt]);
        an[1][nt] = MFMA(a1, bb[nt], an[1][nt]);
      }
    }
    float4_t vm4[2];
    #pragma unroll
    for (int dt = 0; dt < 2; ++dt)
      vm4[dt] = *(const float4_t*)(vmean + hd * 128 + wv * 32 + dt * 16 + lg * 4);
    #pragma unroll
    for (int nt = 0; nt < 4; ++nt){
      float f2 = 0.25f / (denom_l[hd * 64 + nt * 16 + lc] + 1e-8f);
      float f1 = scl_l[hd * 64 + nt * 16 + lc] * f2;
      #pragma unroll
      for (int dt = 0; dt < 2; ++dt)
        #pragma unroll
        for (int r = 0; r < 4; ++r)
          macc[dt][nt][r] += an[dt][nt][r] * f1 + vm4[dt][r] * f2;
    }
  }
  __syncthreads();                                 // B4: qlds reads done -> X may alias
  #pragma unroll
  for (int dt = 0; dt < 2; ++dt)
    #pragma unroll
    for (int nt = 0; nt < 4; ++nt){
      int tok = nt * 16 + lc;
      int d0 = wv * 32 + dt * 16 + lg * 4;
      float4_t ox;
      #pragma unroll
      for (int r = 0; r < 4; ++r)
        ox[r] = 0.5f * macc[dt][nt][r] + 0.5f * bf2f((ushort)hres[dt][nt][r]);
      *(float4_t*)((char*)X + tok * 512 + ((d0 * 4) ^ ((tok & 7) << 4))) = ox;  // 16B aligned b128 store
    }
  __syncthreads();                                 // B5: X ready

  // ---- group-parallel LN: each 16-lane group owns one token; lane holds 8 channels ----
  float g1v[8], b1v[8];
  {
    float4_t ga = *(const float4_t*)(g1 + lc * 8);
    float4_t gb = *(const float4_t*)(g1 + lc * 8 + 4);
    float4_t ba = *(const float4_t*)(b1 + lc * 8);
    float4_t bb = *(const float4_t*)(b1 + lc * 8 + 4);
    #pragma unroll
    for (int j = 0; j < 4; ++j){ g1v[j] = ga[j]; g1v[j + 4] = gb[j]; b1v[j] = ba[j]; b1v[j + 4] = bb[j]; }
  }
  for (int it = 0; it < 4; ++it){
    int tokl = wv * 16 + it * 4 + lg;
    int sw = (tokl & 7) << 4;
    float4_t xa = *(const float4_t*)((char*)X + tokl * 512 + ((lc * 32) ^ sw));
    float4_t xb = *(const float4_t*)((char*)X + tokl * 512 + ((lc * 32 + 16) ^ sw));
    float s = ((xa[0] + xa[1]) + (xa[2] + xa[3])) + ((xb[0] + xb[1]) + (xb[2] + xb[3]));
    s += __shfl_xor(s, 1); s += __shfl_xor(s, 2);
    s += __shfl_xor(s, 4); s += __shfl_xor(s, 8);
    float mean = s * 0.0078125f;
    float ssq = 0.f;
    #pragma unroll
    for (int j = 0; j < 4; ++j){
      float da = xa[j] - mean, db = xb[j] - mean;
      ssq += da * da + db * db;
    }
    ssq += __shfl_xor(ssq, 1); ssq += __shfl_xor(ssq, 2);
    ssq += __shfl_xor(ssq, 4); ssq += __shfl_xor(ssq, 8);
    float rstd = rsqrtf(ssq * 0.0078125f + 1e-5f);
    float4_t oa, ob;
    #pragma unroll
    for (int j = 0; j < 4; ++j){
      oa[j] = fmaf((xa[j] - mean) * rstd, g1v[j], b1v[j]);
      ob[j] = fmaf((xb[j] - mean) * rstd, g1v[j + 4], b1v[j + 4]);
    }
    size_t gtok = (size_t)tok0 + tokl;
    *(float4_t*)(out + gtok * 128 + lc * 8) = oa;
    *(float4_t*)(out + gtok * 128 + lc * 8 + 4) = ob;
  }
}

extern "C" void kernel_launch(void* const* d_in, const int* in_sizes, int n_in,
                              void* d_out, int out_size, void* d_ws, size_t ws_size,
                              hipStream_t stream){
  (void)in_sizes; (void)n_in; (void)out_size; (void)ws_size;
  const float* x    = (const float*)d_in[0];
  const float* fc0w = (const float*)d_in[1];
  const float* fc0b = (const float*)d_in[2];
  const float* ln0g = (const float*)d_in[3];
  const float* ln0b = (const float*)d_in[4];
  const float* wqw  = (const float*)d_in[5];
  const float* wqb  = (const float*)d_in[6];
  const float* wkw  = (const float*)d_in[7];
  const float* wkb  = (const float*)d_in[8];
  const float* wvw  = (const float*)d_in[9];
  const float* wvb  = (const float*)d_in[10];
  const float* ln1g = (const float*)d_in[11];
  const float* ln1b = (const float*)d_in[12];
  float* out = (float*)d_out;
  char* ws = (char*)d_ws;

  ushort* hbf   = (ushort*)(ws);                                  // LPAD*128 bf16 = 43,515,904 B
  ushort* wqT   = (ushort*)(ws + 43515904);                       // 131072 B
  ushort* wkT   = (ushort*)(ws + 43515904 + 131072);
  ushort* wvT   = (ushort*)(ws + 43515904 + 262144);
  ushort* kvsT  = (ushort*)(ws + 43515904 + 393216);              // 131072 B
  float*  ksum  = (float*)(ws + 43515904 + 524288);               // 2048 B
  float*  vmean = (float*)(ws + 43515904 + 526336);               // 2048 B
  float*  kvsP  = (float*)(ws + 43515904 + 528384);               // 166*4*16384*4 = 43,515,904 B
  float*  ksvP  = (float*)(ws + 43515904 + 528384 + 43515904);    // 166*4*256*4 = 679,936 B

  hipLaunchKernelGGL(prep_w_kernel, dim3(768), dim3(256), 0, stream, wqw, wkw, wvw, wqT, wkT, wvT);
  hipLaunchKernelGGL(fc0_kernel, dim3(5312), dim3(256), 0, stream, x, fc0w, fc0b, ln0g, ln0b, hbf);
  hipLaunchKernelGGL(kv_kernel, dim3(664), dim3(512), 0, stream, hbf, wkT, wvT, wkb, wvb, kvsP, ksvP);
  hipLaunchKernelGGL(reduce_kernel, dim3(260), dim3(256), 0, stream, kvsP, ksvP, kvsT, ksum, vmean);
  hipLaunchKernelGGL(attn_kernel, dim3(2649), dim3(256), 0, stream, hbf, wqT, wqb, kvsT, ksum, vmean, ln1g, ln1b, out);
}